// Round 1
// baseline (370.793 us; speedup 1.0000x reference)
//
#include <hip/hip_runtime.h>
#include <hip/hip_bf16.h>
#include <math.h>

#define T_STEPS 65536
#define DDIM 256
#define RDIM 32
#define MDIM 52
#define CHUNK 64
#define NCH (T_STEPS / CHUNK)   // 1024

// ---------------------------------------------------------------------------
// Kernel 1: fused projections.  PROJ[t][0:32]=k, [32:64]=v, [64:96]=q
// GEMM 65536 x 96 x 256, fp32 VALU, LDS-tiled (BM=64, BN=96, BK=64),
// per-thread micro-tile 4 rows x 6 cols.
// ---------------------------------------------------------------------------
__global__ __launch_bounds__(256) void proj_kernel(
    const float* __restrict__ X,
    const float* __restrict__ Wk, const float* __restrict__ bk,
    const float* __restrict__ Wv, const float* __restrict__ bv,
    const float* __restrict__ Wq, const float* __restrict__ bq,
    float* __restrict__ PROJ)
{
    __shared__ float Xs[64][68];   // pad 68: rows land on distinct banks
    __shared__ float Ws[96][68];
    const int tid = threadIdx.x;
    const int t0  = blockIdx.x * 64;
    const int tx  = tid & 15;      // cols {tx + 16j}, j=0..5  (2-way bank alias: free)
    const int ty  = tid >> 4;      // rows {ty*4 + i}, i=0..3

    float acc[4][6];
#pragma unroll
    for (int i = 0; i < 4; i++)
#pragma unroll
        for (int j = 0; j < 6; j++) acc[i][j] = 0.f;

    for (int k0 = 0; k0 < DDIM; k0 += 64) {
        __syncthreads();
        // stage X tile: 64x64 floats (coalesced float4)
#pragma unroll
        for (int u = 0; u < 4; u++) {
            int f = tid + 256 * u;          // 0..1023 float4 slots
            int row = f >> 4, c4 = (f & 15) * 4;
            float4 xv = *(const float4*)(X + (size_t)(t0 + row) * DDIM + k0 + c4);
            *(float4*)(&Xs[row][c4]) = xv;
        }
        // stage W tile: 96x64 floats
#pragma unroll
        for (int u = 0; u < 6; u++) {
            int f = tid + 256 * u;          // 0..1535
            int wr = f >> 4, c4 = (f & 15) * 4;
            const float* src = (wr < 32) ? (Wk + (size_t)wr * DDIM)
                             : (wr < 64) ? (Wv + (size_t)(wr - 32) * DDIM)
                                         : (Wq + (size_t)(wr - 64) * DDIM);
            float4 wv = *(const float4*)(src + k0 + c4);
            *(float4*)(&Ws[wr][c4]) = wv;
        }
        __syncthreads();
#pragma unroll 4
        for (int kk = 0; kk < 64; kk += 4) {
            float4 a[4], w[6];
#pragma unroll
            for (int i = 0; i < 4; i++) a[i] = *(const float4*)(&Xs[ty * 4 + i][kk]);
#pragma unroll
            for (int j = 0; j < 6; j++) w[j] = *(const float4*)(&Ws[tx + 16 * j][kk]);
#pragma unroll
            for (int i = 0; i < 4; i++)
#pragma unroll
                for (int j = 0; j < 6; j++) {
                    acc[i][j] += a[i].x * w[j].x + a[i].y * w[j].y
                               + a[i].z * w[j].z + a[i].w * w[j].w;
                }
        }
    }
#pragma unroll
    for (int j = 0; j < 6; j++) {
        int col = tx + 16 * j;
        float bias = (col < 32) ? bk[col] : (col < 64) ? bv[col - 32] : bq[col - 64];
#pragma unroll
        for (int i = 0; i < 4; i++) {
            int row = t0 + ty * 4 + i;
            PROJ[(size_t)row * 96 + col] = acc[i][j] + bias;
        }
    }
}

// ---------------------------------------------------------------------------
// Kernel 2 (Phase A): per-chunk decay product P and sum S = sum_s (P/b_s) l_s k_s v_s^T
// ---------------------------------------------------------------------------
__global__ __launch_bounds__(256) void phaseA_kernel(
    const float* __restrict__ PROJ,
    const float* __restrict__ lr, const float* __restrict__ decay,
    float* __restrict__ Schunk,   // [NCH][32*32]
    float* __restrict__ Pchunk)   // [NCH]
{
    __shared__ float dl[CHUNK], ll[CHUNK], bb[CHUNK];
    __shared__ float ks[CHUNK][36];   // (P/b_s) l_s k_s
    __shared__ float vs[CHUNK][36];
    const int tid = threadIdx.x;
    const int ch  = blockIdx.x;
    const int t0  = ch * CHUNK;

    if (tid < CHUNK) { dl[tid] = decay[t0 + tid]; ll[tid] = lr[t0 + tid]; }
    __syncthreads();
    if (tid < CHUNK) {                 // O(C^2) dumb-parallel cumprod: trivial
        float b = 1.f;
        for (int j = 0; j <= tid; j++) b *= (1.f - dl[j]);
        bb[tid] = b;
    }
    __syncthreads();
    const float P = bb[CHUNK - 1];

#pragma unroll
    for (int u = 0; u < 2; u++) {
        int f4 = tid + 256 * u;        // 0..511 float4 slots over 64x32
        int s = f4 >> 3, c4 = (f4 & 7) * 4;
        float sk = (P / bb[s]) * ll[s];
        float4 kv = *(const float4*)(PROJ + (size_t)(t0 + s) * 96 + c4);
        kv.x *= sk; kv.y *= sk; kv.z *= sk; kv.w *= sk;
        *(float4*)(&ks[s][c4]) = kv;
        float4 vv = *(const float4*)(PROJ + (size_t)(t0 + s) * 96 + 32 + c4);
        *(float4*)(&vs[s][c4]) = vv;
    }
    __syncthreads();

    const int b  = tid & 31;
    const int ag = tid >> 5;           // 0..7; a = ag + 8i
    float acc[4] = {0.f, 0.f, 0.f, 0.f};
    for (int s = 0; s < CHUNK; s++) {
        float vv = vs[s][b];
#pragma unroll
        for (int i = 0; i < 4; i++) acc[i] += ks[s][ag + 8 * i] * vv;
    }
    float* Sout = Schunk + (size_t)ch * 1024;
#pragma unroll
    for (int i = 0; i < 4; i++) Sout[(ag + 8 * i) * 32 + b] = acc[i];
    if (tid == 0) Pchunk[ch] = P;
}

// ---------------------------------------------------------------------------
// Kernel 3 (Phase B): element-wise sequential scan over chunks.
// Wstart[ch] = state BEFORE chunk ch.  1024 independent threads.
// ---------------------------------------------------------------------------
__global__ __launch_bounds__(256) void phaseB_kernel(
    const float* __restrict__ Schunk, const float* __restrict__ Pchunk,
    float* __restrict__ Wstart)
{
    const int e = blockIdx.x * 256 + threadIdx.x;   // 0..1023
    float w = 0.f;
#pragma unroll 4
    for (int ch = 0; ch < NCH; ch++) {
        Wstart[(size_t)ch * 1024 + e] = w;
        w = Pchunk[ch] * w + Schunk[(size_t)ch * 1024 + e];
    }
}

// ---------------------------------------------------------------------------
// Kernel 4 (Phase C): intra-chunk attention + carried state + fused epilogue.
// out[t] = 1 + tanh( (q̃_t W_start + sum_{s<=t} (q̃_t·k̃_s) v_s) Wo^T + bo )
// ---------------------------------------------------------------------------
__global__ __launch_bounds__(256) void phaseC_kernel(
    const float* __restrict__ PROJ,
    const float* __restrict__ lr, const float* __restrict__ decay,
    const float* __restrict__ Wstart,
    const float* __restrict__ Wo, const float* __restrict__ bo,
    float* __restrict__ out)
{
    __shared__ float dl[CHUNK], ll[CHUNK], bb[CHUNK];
    __shared__ float qs[CHUNK][36];    // b_t * q_t
    __shared__ float kTs[32][68];      // transposed (l_s/b_s) k_s : [a][s]
    __shared__ float vs[CHUNK][36];
    __shared__ float Wst[32][36];
    __shared__ float sc[CHUNK][65];    // masked scores
    __shared__ float fast[CHUNK][33];
    __shared__ float Wos[MDIM][33];
    __shared__ float bos[MDIM];
    const int tid = threadIdx.x;
    const int ch  = blockIdx.x;
    const int t0  = ch * CHUNK;

    if (tid < CHUNK) { dl[tid] = decay[t0 + tid]; ll[tid] = lr[t0 + tid]; }
    __syncthreads();
    if (tid < CHUNK) {
        float b = 1.f;
        for (int j = 0; j <= tid; j++) b *= (1.f - dl[j]);
        bb[tid] = b;
    }
    __syncthreads();

    // stage q̃, k̃^T, v
#pragma unroll
    for (int u = 0; u < 2; u++) {
        int f4 = tid + 256 * u;        // 0..511 float4 slots
        int s = f4 >> 3, c4 = (f4 & 7) * 4;
        float bs = bb[s];
        float4 qv = *(const float4*)(PROJ + (size_t)(t0 + s) * 96 + 64 + c4);
        qv.x *= bs; qv.y *= bs; qv.z *= bs; qv.w *= bs;
        *(float4*)(&qs[s][c4]) = qv;
        float4 vv = *(const float4*)(PROJ + (size_t)(t0 + s) * 96 + 32 + c4);
        *(float4*)(&vs[s][c4]) = vv;
        float sk = ll[s] / bs;
        float4 kv = *(const float4*)(PROJ + (size_t)(t0 + s) * 96 + c4);
        kTs[c4 + 0][s] = kv.x * sk;
        kTs[c4 + 1][s] = kv.y * sk;
        kTs[c4 + 2][s] = kv.z * sk;
        kTs[c4 + 3][s] = kv.w * sk;
    }
    // stage Wstart (32x32)
    {
        float4 wv = *(const float4*)(Wstart + (size_t)ch * 1024 + tid * 4);
        int a = tid >> 3, r = (tid & 7) * 4;
        *(float4*)(&Wst[a][r]) = wv;
    }
    // stage Wo, bo
    for (int f = tid; f < MDIM * 32; f += 256) Wos[f >> 5][f & 31] = Wo[f];
    if (tid < MDIM) bos[tid] = bo[tid];
    __syncthreads();

    // scores: 64x64, lower triangle (incl diag), masked zeros elsewhere
    {
        const int s  = tid & 63;       // lane dim
        const int tg = tid >> 6;       // wave id -> t uniform per wave (broadcast q̃)
#pragma unroll
        for (int i = 0; i < 16; i++) {
            int t = tg + 4 * i;
            float d = 0.f;
#pragma unroll
            for (int j = 0; j < 32; j += 4) {
                float4 qv = *(const float4*)(&qs[t][j]);
                d += qv.x * kTs[j][s] + qv.y * kTs[j + 1][s]
                   + qv.z * kTs[j + 2][s] + qv.w * kTs[j + 3][s];
            }
            sc[t][s] = (s <= t) ? d : 0.f;
        }
    }
    __syncthreads();

    // fast_out: 64x32, per-thread tile 2t x 4r
    {
        const int rt  = tid & 7;
        const int tt  = tid >> 3;
        const int r0  = rt * 4;
        const int tl0 = tt * 2;
        float o00 = 0, o01 = 0, o02 = 0, o03 = 0, o10 = 0, o11 = 0, o12 = 0, o13 = 0;
#pragma unroll 4
        for (int a = 0; a < 32; a++) {
            float4 wv = *(const float4*)(&Wst[a][r0]);
            float q0 = qs[tl0][a], q1 = qs[tl0 + 1][a];
            o00 += q0 * wv.x; o01 += q0 * wv.y; o02 += q0 * wv.z; o03 += q0 * wv.w;
            o10 += q1 * wv.x; o11 += q1 * wv.y; o12 += q1 * wv.z; o13 += q1 * wv.w;
        }
#pragma unroll 4
        for (int s = 0; s < CHUNK; s++) {
            float4 vv = *(const float4*)(&vs[s][r0]);
            float s0 = sc[tl0][s], s1 = sc[tl0 + 1][s];
            o00 += s0 * vv.x; o01 += s0 * vv.y; o02 += s0 * vv.z; o03 += s0 * vv.w;
            o10 += s1 * vv.x; o11 += s1 * vv.y; o12 += s1 * vv.z; o13 += s1 * vv.w;
        }
        fast[tl0][r0] = o00; fast[tl0][r0 + 1] = o01; fast[tl0][r0 + 2] = o02; fast[tl0][r0 + 3] = o03;
        fast[tl0 + 1][r0] = o10; fast[tl0 + 1][r0 + 1] = o11; fast[tl0 + 1][r0 + 2] = o12; fast[tl0 + 1][r0 + 3] = o13;
    }
    __syncthreads();

    // epilogue: raw = fast @ Wo^T + bo ; out = 1 + tanh(raw)
    for (int f = tid; f < CHUNK * MDIM; f += 256) {
        int t = f / MDIM, m = f % MDIM;
        float acc = bos[m];
#pragma unroll
        for (int r = 0; r < 32; r += 4) {
            acc += fast[t][r] * Wos[m][r] + fast[t][r + 1] * Wos[m][r + 1]
                 + fast[t][r + 2] * Wos[m][r + 2] + fast[t][r + 3] * Wos[m][r + 3];
        }
        out[(size_t)(t0 + t) * MDIM + m] = 1.f + tanhf(acc);
    }
}

// ---------------------------------------------------------------------------
extern "C" void kernel_launch(void* const* d_in, const int* in_sizes, int n_in,
                              void* d_out, int out_size, void* d_ws, size_t ws_size,
                              hipStream_t stream) {
    (void)in_sizes; (void)n_in; (void)out_size; (void)ws_size;
    const float* X   = (const float*)d_in[0];
    const float* lr  = (const float*)d_in[1];
    const float* dec = (const float*)d_in[2];
    const float* Wk  = (const float*)d_in[3];
    const float* bk  = (const float*)d_in[4];
    const float* Wv  = (const float*)d_in[5];
    const float* bv  = (const float*)d_in[6];
    const float* Wq  = (const float*)d_in[7];
    const float* bq  = (const float*)d_in[8];
    const float* Wo  = (const float*)d_in[9];
    const float* bo  = (const float*)d_in[10];
    float* out = (float*)d_out;

    // workspace layout (floats): PROJ[T*96] | S[NCH*1024] | P[NCH] | Wstart[NCH*1024]
    float* ws   = (float*)d_ws;
    float* PROJ = ws;
    float* S    = PROJ + (size_t)T_STEPS * 96;
    float* P    = S + (size_t)NCH * 1024;
    float* Wst  = P + NCH;

    proj_kernel<<<T_STEPS / 64, 256, 0, stream>>>(X, Wk, bk, Wv, bv, Wq, bq, PROJ);
    phaseA_kernel<<<NCH, 256, 0, stream>>>(PROJ, lr, dec, S, P);
    phaseB_kernel<<<4, 256, 0, stream>>>(S, P, Wst);
    phaseC_kernel<<<NCH, 256, 0, stream>>>(PROJ, lr, dec, Wst, Wo, bo, out);
}

// Round 2
// 250.628 us; speedup vs baseline: 1.4795x; 1.4795x over previous
//
#include <hip/hip_runtime.h>
#include <hip/hip_bf16.h>
#include <math.h>

#define T_STEPS 65536
#define DDIM 256
#define RDIM 32
#define MDIM 52
#define CHUNK 64
#define NCH (T_STEPS / CHUNK)   // 1024 chunks
#define SCH 32                  // chunks per superchunk
#define NSC (NCH / SCH)         // 32 superchunks

// ---------------------------------------------------------------------------
// Kernel 1: fused projections.  PROJ[t][0:32]=k, [32:64]=v, [64:96]=q
// GEMM 65536 x 96 x 256, fp32 VALU, LDS-tiled (BM=64, BN=96, BK=64),
// per-thread micro-tile 4 rows x 6 cols.
// ---------------------------------------------------------------------------
__global__ __launch_bounds__(256) void proj_kernel(
    const float* __restrict__ X,
    const float* __restrict__ Wk, const float* __restrict__ bk,
    const float* __restrict__ Wv, const float* __restrict__ bv,
    const float* __restrict__ Wq, const float* __restrict__ bq,
    float* __restrict__ PROJ)
{
    __shared__ float Xs[64][68];   // pad 68: rows land on distinct banks
    __shared__ float Ws[96][68];
    const int tid = threadIdx.x;
    const int t0  = blockIdx.x * 64;
    const int tx  = tid & 15;      // cols {tx + 16j}, j=0..5  (2-way bank alias: free)
    const int ty  = tid >> 4;      // rows {ty*4 + i}, i=0..3

    float acc[4][6];
#pragma unroll
    for (int i = 0; i < 4; i++)
#pragma unroll
        for (int j = 0; j < 6; j++) acc[i][j] = 0.f;

    for (int k0 = 0; k0 < DDIM; k0 += 64) {
        __syncthreads();
        // stage X tile: 64x64 floats (coalesced float4)
#pragma unroll
        for (int u = 0; u < 4; u++) {
            int f = tid + 256 * u;          // 0..1023 float4 slots
            int row = f >> 4, c4 = (f & 15) * 4;
            float4 xv = *(const float4*)(X + (size_t)(t0 + row) * DDIM + k0 + c4);
            *(float4*)(&Xs[row][c4]) = xv;
        }
        // stage W tile: 96x64 floats
#pragma unroll
        for (int u = 0; u < 6; u++) {
            int f = tid + 256 * u;          // 0..1535
            int wr = f >> 4, c4 = (f & 15) * 4;
            const float* src = (wr < 32) ? (Wk + (size_t)wr * DDIM)
                             : (wr < 64) ? (Wv + (size_t)(wr - 32) * DDIM)
                                         : (Wq + (size_t)(wr - 64) * DDIM);
            float4 wv = *(const float4*)(src + k0 + c4);
            *(float4*)(&Ws[wr][c4]) = wv;
        }
        __syncthreads();
#pragma unroll 4
        for (int kk = 0; kk < 64; kk += 4) {
            float4 a[4], w[6];
#pragma unroll
            for (int i = 0; i < 4; i++) a[i] = *(const float4*)(&Xs[ty * 4 + i][kk]);
#pragma unroll
            for (int j = 0; j < 6; j++) w[j] = *(const float4*)(&Ws[tx + 16 * j][kk]);
#pragma unroll
            for (int i = 0; i < 4; i++)
#pragma unroll
                for (int j = 0; j < 6; j++) {
                    acc[i][j] += a[i].x * w[j].x + a[i].y * w[j].y
                               + a[i].z * w[j].z + a[i].w * w[j].w;
                }
        }
    }
#pragma unroll
    for (int j = 0; j < 6; j++) {
        int col = tx + 16 * j;
        float bias = (col < 32) ? bk[col] : (col < 64) ? bv[col - 32] : bq[col - 64];
#pragma unroll
        for (int i = 0; i < 4; i++) {
            int row = t0 + ty * 4 + i;
            PROJ[(size_t)row * 96 + col] = acc[i][j] + bias;
        }
    }
}

// ---------------------------------------------------------------------------
// Kernel 2 (Phase A): per-chunk decay product P and sum S = sum_s (P/b_s) l_s k_s v_s^T
// ---------------------------------------------------------------------------
__global__ __launch_bounds__(256) void phaseA_kernel(
    const float* __restrict__ PROJ,
    const float* __restrict__ lr, const float* __restrict__ decay,
    float* __restrict__ Schunk,   // [NCH][32*32]
    float* __restrict__ Pchunk)   // [NCH]
{
    __shared__ float dl[CHUNK], ll[CHUNK], bb[CHUNK];
    __shared__ float ks[CHUNK][36];   // (P/b_s) l_s k_s
    __shared__ float vs[CHUNK][36];
    const int tid = threadIdx.x;
    const int ch  = blockIdx.x;
    const int t0  = ch * CHUNK;

    if (tid < CHUNK) { dl[tid] = decay[t0 + tid]; ll[tid] = lr[t0 + tid]; }
    __syncthreads();
    if (tid < CHUNK) {                 // O(C^2) dumb-parallel cumprod: trivial
        float b = 1.f;
        for (int j = 0; j <= tid; j++) b *= (1.f - dl[j]);
        bb[tid] = b;
    }
    __syncthreads();
    const float P = bb[CHUNK - 1];

#pragma unroll
    for (int u = 0; u < 2; u++) {
        int f4 = tid + 256 * u;        // 0..511 float4 slots over 64x32
        int s = f4 >> 3, c4 = (f4 & 7) * 4;
        float sk = (P / bb[s]) * ll[s];
        float4 kv = *(const float4*)(PROJ + (size_t)(t0 + s) * 96 + c4);
        kv.x *= sk; kv.y *= sk; kv.z *= sk; kv.w *= sk;
        *(float4*)(&ks[s][c4]) = kv;
        float4 vv = *(const float4*)(PROJ + (size_t)(t0 + s) * 96 + 32 + c4);
        *(float4*)(&vs[s][c4]) = vv;
    }
    __syncthreads();

    const int b  = tid & 31;
    const int ag = tid >> 5;           // 0..7; a = ag + 8i
    float acc[4] = {0.f, 0.f, 0.f, 0.f};
    for (int s = 0; s < CHUNK; s++) {
        float vv = vs[s][b];
#pragma unroll
        for (int i = 0; i < 4; i++) acc[i] += ks[s][ag + 8 * i] * vv;
    }
    float* Sout = Schunk + (size_t)ch * 1024;
#pragma unroll
    for (int i = 0; i < 4; i++) Sout[(ag + 8 * i) * 32 + b] = acc[i];
    if (tid == 0) Pchunk[ch] = P;
}

// ---------------------------------------------------------------------------
// Kernel 3a (Phase B1): local scan inside each superchunk (32 seq iters).
// Wlocal[ch] = scan state before chunk ch with zero origin at superchunk start.
// AP[ch]     = prod of P over chunks in [sc_start, ch)   (scalar per chunk)
// Wtotal[sc], Atot[sc] = superchunk-composed affine op.
// ---------------------------------------------------------------------------
__global__ __launch_bounds__(256) void phaseB1_kernel(
    const float* __restrict__ Schunk, const float* __restrict__ Pchunk,
    float* __restrict__ Wlocal, float* __restrict__ AP,
    float* __restrict__ Wtotal, float* __restrict__ Atot)
{
    const int sc  = blockIdx.x;
    const int tid = threadIdx.x;
    const int e4  = tid * 4;
    float4 w = make_float4(0.f, 0.f, 0.f, 0.f);
    float  a = 1.f;
#pragma unroll 4
    for (int c = 0; c < SCH; c++) {
        const int ch = sc * SCH + c;
        const float p = Pchunk[ch];           // uniform -> scalar load
        if (tid == 0) AP[ch] = a;
        *(float4*)(Wlocal + (size_t)ch * 1024 + e4) = w;
        float4 s = *(const float4*)(Schunk + (size_t)ch * 1024 + e4);
        w.x = p * w.x + s.x;  w.y = p * w.y + s.y;
        w.z = p * w.z + s.z;  w.w = p * w.w + s.w;
        a *= p;
    }
    *(float4*)(Wtotal + (size_t)sc * 1024 + e4) = w;
    if (tid == 0) Atot[sc] = a;
}

// ---------------------------------------------------------------------------
// Kernel 3b (Phase B2): scan over the 32 superchunk totals (32 seq iters).
// Wsuper[sc] = global state before superchunk sc.
// ---------------------------------------------------------------------------
__global__ __launch_bounds__(256) void phaseB2_kernel(
    const float* __restrict__ Wtotal, const float* __restrict__ Atot,
    float* __restrict__ Wsuper)
{
    const int tid = threadIdx.x;   // single block
    const int e4  = tid * 4;
    float4 w = make_float4(0.f, 0.f, 0.f, 0.f);
#pragma unroll 4
    for (int s = 0; s < NSC; s++) {
        *(float4*)(Wsuper + (size_t)s * 1024 + e4) = w;
        const float p = Atot[s];
        float4 t = *(const float4*)(Wtotal + (size_t)s * 1024 + e4);
        w.x = p * w.x + t.x;  w.y = p * w.y + t.y;
        w.z = p * w.z + t.z;  w.w = p * w.w + t.w;
    }
}

// ---------------------------------------------------------------------------
// Kernel 4 (Phase C): intra-chunk attention + carried state + fused epilogue.
// Wstart[ch] = AP[ch] * Wsuper[sc(ch)] + Wlocal[ch]   (fixup fused here)
// out[t] = 1 + tanh( (q̃_t W_start + sum_{s<=t} (q̃_t·k̃_s) v_s) Wo^T + bo )
// ---------------------------------------------------------------------------
__global__ __launch_bounds__(256) void phaseC_kernel(
    const float* __restrict__ PROJ,
    const float* __restrict__ lr, const float* __restrict__ decay,
    const float* __restrict__ Wlocal, const float* __restrict__ AP,
    const float* __restrict__ Wsuper,
    const float* __restrict__ Wo, const float* __restrict__ bo,
    float* __restrict__ out)
{
    __shared__ float dl[CHUNK], ll[CHUNK], bb[CHUNK];
    __shared__ float qs[CHUNK][36];    // b_t * q_t
    __shared__ float kTs[32][68];      // transposed (l_s/b_s) k_s : [a][s]
    __shared__ float vs[CHUNK][36];
    __shared__ float Wst[32][36];
    __shared__ float sc[CHUNK][65];    // masked scores
    __shared__ float fast[CHUNK][33];
    __shared__ float Wos[MDIM][33];
    __shared__ float bos[MDIM];
    const int tid = threadIdx.x;
    const int ch  = blockIdx.x;
    const int t0  = ch * CHUNK;

    if (tid < CHUNK) { dl[tid] = decay[t0 + tid]; ll[tid] = lr[t0 + tid]; }
    __syncthreads();
    if (tid < CHUNK) {
        float b = 1.f;
        for (int j = 0; j <= tid; j++) b *= (1.f - dl[j]);
        bb[tid] = b;
    }
    __syncthreads();

    // stage q̃, k̃^T, v
#pragma unroll
    for (int u = 0; u < 2; u++) {
        int f4 = tid + 256 * u;        // 0..511 float4 slots
        int s = f4 >> 3, c4 = (f4 & 7) * 4;
        float bs = bb[s];
        float4 qv = *(const float4*)(PROJ + (size_t)(t0 + s) * 96 + 64 + c4);
        qv.x *= bs; qv.y *= bs; qv.z *= bs; qv.w *= bs;
        *(float4*)(&qs[s][c4]) = qv;
        float4 vv = *(const float4*)(PROJ + (size_t)(t0 + s) * 96 + 32 + c4);
        *(float4*)(&vs[s][c4]) = vv;
        float sk = ll[s] / bs;
        float4 kv = *(const float4*)(PROJ + (size_t)(t0 + s) * 96 + c4);
        kTs[c4 + 0][s] = kv.x * sk;
        kTs[c4 + 1][s] = kv.y * sk;
        kTs[c4 + 2][s] = kv.z * sk;
        kTs[c4 + 3][s] = kv.w * sk;
    }
    // stage Wstart = AP[ch]*Wsuper[sc(ch)] + Wlocal[ch]  (32x32)
    {
        const int scid = ch / SCH;
        const float ap = AP[ch];       // uniform -> scalar load
        float4 wl = *(const float4*)(Wlocal + (size_t)ch * 1024 + tid * 4);
        float4 wu = *(const float4*)(Wsuper + (size_t)scid * 1024 + tid * 4);
        float4 wv;
        wv.x = ap * wu.x + wl.x;  wv.y = ap * wu.y + wl.y;
        wv.z = ap * wu.z + wl.z;  wv.w = ap * wu.w + wl.w;
        int a = tid >> 3, r = (tid & 7) * 4;
        *(float4*)(&Wst[a][r]) = wv;
    }
    // stage Wo, bo
    for (int f = tid; f < MDIM * 32; f += 256) Wos[f >> 5][f & 31] = Wo[f];
    if (tid < MDIM) bos[tid] = bo[tid];
    __syncthreads();

    // scores: 64x64, lower triangle (incl diag), masked zeros elsewhere
    {
        const int s  = tid & 63;       // lane dim
        const int tg = tid >> 6;       // wave id -> t uniform per wave (broadcast q̃)
#pragma unroll
        for (int i = 0; i < 16; i++) {
            int t = tg + 4 * i;
            float d = 0.f;
#pragma unroll
            for (int j = 0; j < 32; j += 4) {
                float4 qv = *(const float4*)(&qs[t][j]);
                d += qv.x * kTs[j][s] + qv.y * kTs[j + 1][s]
                   + qv.z * kTs[j + 2][s] + qv.w * kTs[j + 3][s];
            }
            sc[t][s] = (s <= t) ? d : 0.f;
        }
    }
    __syncthreads();

    // fast_out: 64x32, per-thread tile 2t x 4r
    {
        const int rt  = tid & 7;
        const int tt  = tid >> 3;
        const int r0  = rt * 4;
        const int tl0 = tt * 2;
        float o00 = 0, o01 = 0, o02 = 0, o03 = 0, o10 = 0, o11 = 0, o12 = 0, o13 = 0;
#pragma unroll 4
        for (int a = 0; a < 32; a++) {
            float4 wv = *(const float4*)(&Wst[a][r0]);
            float q0 = qs[tl0][a], q1 = qs[tl0 + 1][a];
            o00 += q0 * wv.x; o01 += q0 * wv.y; o02 += q0 * wv.z; o03 += q0 * wv.w;
            o10 += q1 * wv.x; o11 += q1 * wv.y; o12 += q1 * wv.z; o13 += q1 * wv.w;
        }
#pragma unroll 4
        for (int s = 0; s < CHUNK; s++) {
            float4 vv = *(const float4*)(&vs[s][r0]);
            float s0 = sc[tl0][s], s1 = sc[tl0 + 1][s];
            o00 += s0 * vv.x; o01 += s0 * vv.y; o02 += s0 * vv.z; o03 += s0 * vv.w;
            o10 += s1 * vv.x; o11 += s1 * vv.y; o12 += s1 * vv.z; o13 += s1 * vv.w;
        }
        fast[tl0][r0] = o00; fast[tl0][r0 + 1] = o01; fast[tl0][r0 + 2] = o02; fast[tl0][r0 + 3] = o03;
        fast[tl0 + 1][r0] = o10; fast[tl0 + 1][r0 + 1] = o11; fast[tl0 + 1][r0 + 2] = o12; fast[tl0 + 1][r0 + 3] = o13;
    }
    __syncthreads();

    // epilogue: raw = fast @ Wo^T + bo ; out = 1 + tanh(raw)
    for (int f = tid; f < CHUNK * MDIM; f += 256) {
        int t = f / MDIM, m = f % MDIM;
        float acc = bos[m];
#pragma unroll
        for (int r = 0; r < 32; r += 4) {
            acc += fast[t][r] * Wos[m][r] + fast[t][r + 1] * Wos[m][r + 1]
                 + fast[t][r + 2] * Wos[m][r + 2] + fast[t][r + 3] * Wos[m][r + 3];
        }
        out[(size_t)(t0 + t) * MDIM + m] = 1.f + tanhf(acc);
    }
}

// ---------------------------------------------------------------------------
extern "C" void kernel_launch(void* const* d_in, const int* in_sizes, int n_in,
                              void* d_out, int out_size, void* d_ws, size_t ws_size,
                              hipStream_t stream) {
    (void)in_sizes; (void)n_in; (void)out_size; (void)ws_size;
    const float* X   = (const float*)d_in[0];
    const float* lr  = (const float*)d_in[1];
    const float* dec = (const float*)d_in[2];
    const float* Wk  = (const float*)d_in[3];
    const float* bk  = (const float*)d_in[4];
    const float* Wv  = (const float*)d_in[5];
    const float* bv  = (const float*)d_in[6];
    const float* Wq  = (const float*)d_in[7];
    const float* bq  = (const float*)d_in[8];
    const float* Wo  = (const float*)d_in[9];
    const float* bo  = (const float*)d_in[10];
    float* out = (float*)d_out;

    // workspace layout (floats):
    // PROJ[T*96] | S[NCH*1024] | P[NCH] | AP[NCH] | Wlocal[NCH*1024]
    // | Wtotal[NSC*1024] | Atot[NSC] | Wsuper[NSC*1024]
    float* ws    = (float*)d_ws;
    float* PROJ  = ws;
    float* S     = PROJ + (size_t)T_STEPS * 96;
    float* P     = S + (size_t)NCH * 1024;
    float* APb   = P + NCH;
    float* Wloc  = APb + NCH;
    float* Wtot  = Wloc + (size_t)NCH * 1024;
    float* Atot  = Wtot + (size_t)NSC * 1024;
    float* Wsup  = Atot + NSC;

    proj_kernel<<<T_STEPS / 64, 256, 0, stream>>>(X, Wk, bk, Wv, bv, Wq, bq, PROJ);
    phaseA_kernel<<<NCH, 256, 0, stream>>>(PROJ, lr, dec, S, P);
    phaseB1_kernel<<<NSC, 256, 0, stream>>>(S, P, Wloc, APb, Wtot, Atot);
    phaseB2_kernel<<<1, 256, 0, stream>>>(Wtot, Atot, Wsup);
    phaseC_kernel<<<NCH, 256, 0, stream>>>(PROJ, lr, dec, Wloc, APb, Wsup, Wo, bo, out);
}

// Round 3
// 202.242 us; speedup vs baseline: 1.8334x; 1.2392x over previous
//
#include <hip/hip_runtime.h>
#include <hip/hip_bf16.h>
#include <math.h>

#define T_STEPS 65536
#define DDIM 256
#define RDIM 32
#define MDIM 52
#define CHUNK 64
#define NCH (T_STEPS / CHUNK)   // 1024 chunks
#define SCH 32                  // chunks per superchunk
#define NSC (NCH / SCH)         // 32 superchunks

typedef short short8 __attribute__((ext_vector_type(8)));   // 8 bf16 (4 VGPRs)
typedef float f32x4  __attribute__((ext_vector_type(4)));   // MFMA acc

union bf8pack { short8 v; __hip_bfloat16 h[8]; };

// ---------------------------------------------------------------------------
// K0: pack W = [Wk;Wv;Wq] (96x256 fp32) into MFMA B-fragment order, bf16.
// Bfrag[((c*8+kb)*64+lane)*8 + j] = bf16( W[16c+(lane&15)][kb*32+(lane>>4)*8+j] )
// ---------------------------------------------------------------------------
__global__ __launch_bounds__(256) void prepB_kernel(
    const float* __restrict__ Wk, const float* __restrict__ Wv,
    const float* __restrict__ Wq, __hip_bfloat16* __restrict__ Bfrag)
{
    const int idx = blockIdx.x * 256 + threadIdx.x;   // 0..3071
    if (idx >= 6 * 8 * 64) return;
    const int lane = idx & 63;
    const int kb   = (idx >> 6) & 7;
    const int c    = idx >> 9;
    const int row  = 16 * c + (lane & 15);            // 0..95
    const int k0   = kb * 32 + (lane >> 4) * 8;       // 0..248
    const float* src = (row < 32) ? (Wk + (size_t)row * DDIM)
                     : (row < 64) ? (Wv + (size_t)(row - 32) * DDIM)
                                  : (Wq + (size_t)(row - 64) * DDIM);
    bf8pack p;
#pragma unroll
    for (int j = 0; j < 8; j++) p.h[j] = __float2bfloat16(src[k0 + j]);
    *(short8*)(Bfrag + (size_t)idx * 8) = p.v;
}

// ---------------------------------------------------------------------------
// K1: MFMA projections (64x96x256 per block, bf16 in / fp32 acc) fused with
// phase A (per-chunk S, P).  One block = one chunk.  No LDS in the GEMM.
// ---------------------------------------------------------------------------
__global__ __launch_bounds__(256) void projA_kernel(
    const float* __restrict__ X,
    const float* __restrict__ lr, const float* __restrict__ decay,
    const float* __restrict__ bk, const float* __restrict__ bv,
    const float* __restrict__ bq,
    const __hip_bfloat16* __restrict__ Bfrag,
    float* __restrict__ PROJ, float* __restrict__ Schunk,
    float* __restrict__ Pchunk)
{
    __shared__ float ks[CHUNK][36];   // (P/b_s) l_s k_s  (bias applied)
    __shared__ float vs[CHUNK][36];
    __shared__ float bbS[CHUNK], llS[CHUNK];

    const int tid  = threadIdx.x;
    const int wv   = tid >> 6;        // wave id 0..3 -> row-tile
    const int lane = tid & 63;
    const int ch   = blockIdx.x;
    const int t0   = ch * CHUNK;

    // wave 0: decay cumprod via shfl prefix (CHUNK == wavefront == 64)
    if (wv == 0) {
        float b = 1.f - decay[t0 + lane];
        float l = lr[t0 + lane];
#pragma unroll
        for (int d = 1; d < 64; d <<= 1) {
            float o = __shfl_up(b, d, 64);
            if (lane >= d) b *= o;
        }
        bbS[lane] = b; llS[lane] = l;
    }

    // --- MFMA GEMM: C[64x96] = X_tile[64x256] * W^T ---
    const int m  = lane & 15;
    const int q4 = lane >> 4;
    const float* xrow = X + (size_t)(t0 + 16 * wv + m) * DDIM + q4 * 8;

    f32x4 acc[6];
#pragma unroll
    for (int c = 0; c < 6; c++) acc[c] = (f32x4){0.f, 0.f, 0.f, 0.f};

#pragma unroll
    for (int kb = 0; kb < 8; kb++) {
        float4 a0 = *(const float4*)(xrow + kb * 32);
        float4 a1 = *(const float4*)(xrow + kb * 32 + 4);
        bf8pack ap;
        ap.h[0] = __float2bfloat16(a0.x); ap.h[1] = __float2bfloat16(a0.y);
        ap.h[2] = __float2bfloat16(a0.z); ap.h[3] = __float2bfloat16(a0.w);
        ap.h[4] = __float2bfloat16(a1.x); ap.h[5] = __float2bfloat16(a1.y);
        ap.h[6] = __float2bfloat16(a1.z); ap.h[7] = __float2bfloat16(a1.w);
#pragma unroll
        for (int c = 0; c < 6; c++) {
            short8 bf = *(const short8*)(Bfrag + ((size_t)(c * 8 + kb) * 64 + lane) * 8);
            acc[c] = __builtin_amdgcn_mfma_f32_16x16x32_bf16(ap.v, bf, acc[c], 0, 0, 0);
        }
    }

    __syncthreads();                  // bb/ll ready
    const float P = bbS[63];

    // write PROJ + stage k̃ (scaled) and v to LDS
#pragma unroll
    for (int c = 0; c < 6; c++) {
        const int colg = 16 * c + m;
        const float bias = (colg < 32) ? bk[colg]
                         : (colg < 64) ? bv[colg - 32] : bq[colg - 64];
#pragma unroll
        for (int r = 0; r < 4; r++) {
            const int sloc = 16 * wv + 4 * q4 + r;
            const float val = acc[c][r] + bias;
            PROJ[(size_t)(t0 + sloc) * 96 + colg] = val;
            if (c < 2) {
                float sk = (P / bbS[sloc]) * llS[sloc];
                ks[sloc][colg] = val * sk;
            } else if (c < 4) {
                vs[sloc][colg - 32] = val;
            }
        }
    }
    __syncthreads();

    // phase A accumulation: S[a][b] = sum_s k̃[s][a] v[s][b]
    const int b  = tid & 31;
    const int ag = tid >> 5;          // a = ag + 8i
    float a2[4] = {0.f, 0.f, 0.f, 0.f};
    for (int s = 0; s < CHUNK; s++) {
        float vvv = vs[s][b];
#pragma unroll
        for (int i = 0; i < 4; i++) a2[i] += ks[s][ag + 8 * i] * vvv;
    }
    float* Sout = Schunk + (size_t)ch * 1024;
#pragma unroll
    for (int i = 0; i < 4; i++) Sout[(ag + 8 * i) * 32 + b] = a2[i];
    if (tid == 0) Pchunk[ch] = P;
}

// ---------------------------------------------------------------------------
// K2 (B1): local scan inside each superchunk (32 seq iters).
// ---------------------------------------------------------------------------
__global__ __launch_bounds__(256) void phaseB1_kernel(
    const float* __restrict__ Schunk, const float* __restrict__ Pchunk,
    float* __restrict__ Wlocal, float* __restrict__ AP,
    float* __restrict__ Wtotal, float* __restrict__ Atot)
{
    const int sc  = blockIdx.x;
    const int tid = threadIdx.x;
    const int e4  = tid * 4;
    float4 w = make_float4(0.f, 0.f, 0.f, 0.f);
    float  a = 1.f;
#pragma unroll 4
    for (int c = 0; c < SCH; c++) {
        const int ch = sc * SCH + c;
        const float p = Pchunk[ch];
        if (tid == 0) AP[ch] = a;
        *(float4*)(Wlocal + (size_t)ch * 1024 + e4) = w;
        float4 s = *(const float4*)(Schunk + (size_t)ch * 1024 + e4);
        w.x = p * w.x + s.x;  w.y = p * w.y + s.y;
        w.z = p * w.z + s.z;  w.w = p * w.w + s.w;
        a *= p;
    }
    *(float4*)(Wtotal + (size_t)sc * 1024 + e4) = w;
    if (tid == 0) Atot[sc] = a;
}

// ---------------------------------------------------------------------------
// K3 (B2): scan over the 32 superchunk totals.
// ---------------------------------------------------------------------------
__global__ __launch_bounds__(256) void phaseB2_kernel(
    const float* __restrict__ Wtotal, const float* __restrict__ Atot,
    float* __restrict__ Wsuper)
{
    const int tid = threadIdx.x;
    const int e4  = tid * 4;
    float4 w = make_float4(0.f, 0.f, 0.f, 0.f);
#pragma unroll 4
    for (int s = 0; s < NSC; s++) {
        *(float4*)(Wsuper + (size_t)s * 1024 + e4) = w;
        const float p = Atot[s];
        float4 t = *(const float4*)(Wtotal + (size_t)s * 1024 + e4);
        w.x = p * w.x + t.x;  w.y = p * w.y + t.y;
        w.z = p * w.z + t.z;  w.w = p * w.w + t.w;
    }
}

// ---------------------------------------------------------------------------
// K4 (phase C): intra-chunk attention + carried state + fused epilogue.
// LDS cut to <48KB (3 blocks/CU): scores in bf16, `fast` aliased onto kTs.
// ---------------------------------------------------------------------------
__global__ __launch_bounds__(256) void phaseC_kernel(
    const float* __restrict__ PROJ,
    const float* __restrict__ lr, const float* __restrict__ decay,
    const float* __restrict__ Wlocal, const float* __restrict__ AP,
    const float* __restrict__ Wsuper,
    const float* __restrict__ Wo, const float* __restrict__ bo,
    float* __restrict__ out)
{
    __shared__ float bb[CHUNK], ll[CHUNK];
    __shared__ float qs[CHUNK][36];          // b_t * q_t
    __shared__ float kTs[32][68];            // [a][s]; aliased by `fast` later
    __shared__ float vs[CHUNK][36];
    __shared__ float Wst[32][36];
    __shared__ __hip_bfloat16 scb[CHUNK][66];// masked scores (bf16)
    __shared__ float Wos[MDIM][33];
    __shared__ float bos[MDIM];
    float* fastp = &kTs[0][0];               // fast[t][r] = fastp[t*33+r] (2112<=2176)

    const int tid  = threadIdx.x;
    const int wv   = tid >> 6;
    const int lane = tid & 63;
    const int ch   = blockIdx.x;
    const int t0   = ch * CHUNK;

    // wave 0: decay cumprod via shfl prefix
    if (wv == 0) {
        float b = 1.f - decay[t0 + lane];
        float l = lr[t0 + lane];
#pragma unroll
        for (int d = 1; d < 64; d <<= 1) {
            float o = __shfl_up(b, d, 64);
            if (lane >= d) b *= o;
        }
        bb[lane] = b; ll[lane] = l;
    }
    __syncthreads();

    // stage q̃, k̃^T, v
#pragma unroll
    for (int u = 0; u < 2; u++) {
        int f4 = tid + 256 * u;
        int s = f4 >> 3, c4 = (f4 & 7) * 4;
        float bs = bb[s];
        float4 qv = *(const float4*)(PROJ + (size_t)(t0 + s) * 96 + 64 + c4);
        qv.x *= bs; qv.y *= bs; qv.z *= bs; qv.w *= bs;
        *(float4*)(&qs[s][c4]) = qv;
        float4 vv = *(const float4*)(PROJ + (size_t)(t0 + s) * 96 + 32 + c4);
        *(float4*)(&vs[s][c4]) = vv;
        float sk = ll[s] / bs;
        float4 kv = *(const float4*)(PROJ + (size_t)(t0 + s) * 96 + c4);
        kTs[c4 + 0][s] = kv.x * sk;
        kTs[c4 + 1][s] = kv.y * sk;
        kTs[c4 + 2][s] = kv.z * sk;
        kTs[c4 + 3][s] = kv.w * sk;
    }
    // stage Wstart = AP[ch]*Wsuper[sc(ch)] + Wlocal[ch]
    {
        const int scid = ch / SCH;
        const float ap = AP[ch];
        float4 wl = *(const float4*)(Wlocal + (size_t)ch * 1024 + tid * 4);
        float4 wu = *(const float4*)(Wsuper + (size_t)scid * 1024 + tid * 4);
        float4 wvv;
        wvv.x = ap * wu.x + wl.x;  wvv.y = ap * wu.y + wl.y;
        wvv.z = ap * wu.z + wl.z;  wvv.w = ap * wu.w + wl.w;
        int a = tid >> 3, r = (tid & 7) * 4;
        *(float4*)(&Wst[a][r]) = wvv;
    }
    for (int f = tid; f < MDIM * 32; f += 256) Wos[f >> 5][f & 31] = Wo[f];
    if (tid < MDIM) bos[tid] = bo[tid];
    __syncthreads();

    // scores (lower triangle incl diag), stored bf16
    {
        const int s = lane;
#pragma unroll
        for (int i = 0; i < 16; i++) {
            int t = wv + 4 * i;
            float d = 0.f;
#pragma unroll
            for (int j = 0; j < 32; j += 4) {
                float4 qv = *(const float4*)(&qs[t][j]);
                d += qv.x * kTs[j][s] + qv.y * kTs[j + 1][s]
                   + qv.z * kTs[j + 2][s] + qv.w * kTs[j + 3][s];
            }
            scb[t][s] = __float2bfloat16((s <= t) ? d : 0.f);
        }
    }
    __syncthreads();

    // fast_out: 64x32, per-thread tile 2t x 4r (writes alias kTs — dead now)
    {
        const int r0  = (tid & 7) * 4;
        const int tl0 = (tid >> 3) * 2;
        float o00 = 0, o01 = 0, o02 = 0, o03 = 0, o10 = 0, o11 = 0, o12 = 0, o13 = 0;
#pragma unroll 4
        for (int a = 0; a < 32; a++) {
            float4 wvv = *(const float4*)(&Wst[a][r0]);
            float q0 = qs[tl0][a], q1 = qs[tl0 + 1][a];
            o00 += q0 * wvv.x; o01 += q0 * wvv.y; o02 += q0 * wvv.z; o03 += q0 * wvv.w;
            o10 += q1 * wvv.x; o11 += q1 * wvv.y; o12 += q1 * wvv.z; o13 += q1 * wvv.w;
        }
#pragma unroll 4
        for (int s = 0; s < CHUNK; s++) {
            float4 vv = *(const float4*)(&vs[s][r0]);
            float s0 = __bfloat162float(scb[tl0][s]);
            float s1 = __bfloat162float(scb[tl0 + 1][s]);
            o00 += s0 * vv.x; o01 += s0 * vv.y; o02 += s0 * vv.z; o03 += s0 * vv.w;
            o10 += s1 * vv.x; o11 += s1 * vv.y; o12 += s1 * vv.z; o13 += s1 * vv.w;
        }
        __syncthreads();   // everyone done reading kTs before aliasing writes
        fastp[tl0 * 33 + r0 + 0] = o00; fastp[tl0 * 33 + r0 + 1] = o01;
        fastp[tl0 * 33 + r0 + 2] = o02; fastp[tl0 * 33 + r0 + 3] = o03;
        fastp[(tl0 + 1) * 33 + r0 + 0] = o10; fastp[(tl0 + 1) * 33 + r0 + 1] = o11;
        fastp[(tl0 + 1) * 33 + r0 + 2] = o12; fastp[(tl0 + 1) * 33 + r0 + 3] = o13;
    }
    __syncthreads();

    // epilogue: out = 1 + tanh(fast @ Wo^T + bo) = 2 / (1 + exp(-2*raw))
    for (int f = tid; f < CHUNK * MDIM; f += 256) {
        int t = f / MDIM, mm = f % MDIM;
        float acc = bos[mm];
#pragma unroll
        for (int r = 0; r < 32; r += 4) {
            acc += fastp[t * 33 + r]     * Wos[mm][r]
                 + fastp[t * 33 + r + 1] * Wos[mm][r + 1]
                 + fastp[t * 33 + r + 2] * Wos[mm][r + 2]
                 + fastp[t * 33 + r + 3] * Wos[mm][r + 3];
        }
        out[(size_t)(t0 + t) * MDIM + mm] = 2.0f / (1.0f + __expf(-2.0f * acc));
    }
}

// ---------------------------------------------------------------------------
extern "C" void kernel_launch(void* const* d_in, const int* in_sizes, int n_in,
                              void* d_out, int out_size, void* d_ws, size_t ws_size,
                              hipStream_t stream) {
    (void)in_sizes; (void)n_in; (void)out_size; (void)ws_size;
    const float* X   = (const float*)d_in[0];
    const float* lr  = (const float*)d_in[1];
    const float* dec = (const float*)d_in[2];
    const float* Wk  = (const float*)d_in[3];
    const float* bk  = (const float*)d_in[4];
    const float* Wv  = (const float*)d_in[5];
    const float* bv  = (const float*)d_in[6];
    const float* Wq  = (const float*)d_in[7];
    const float* bq  = (const float*)d_in[8];
    const float* Wo  = (const float*)d_in[9];
    const float* bo  = (const float*)d_in[10];
    float* out = (float*)d_out;

    // workspace layout (floats):
    // PROJ[T*96] | S[NCH*1024] | P[NCH] | AP[NCH] | Wlocal[NCH*1024]
    // | Wtotal[NSC*1024] | Atot[NSC] | Wsuper[NSC*1024] | Bfrag (bf16, 96*256)
    float* ws    = (float*)d_ws;
    float* PROJ  = ws;
    float* S     = PROJ + (size_t)T_STEPS * 96;
    float* P     = S + (size_t)NCH * 1024;
    float* APb   = P + NCH;
    float* Wloc  = APb + NCH;
    float* Wtot  = Wloc + (size_t)NCH * 1024;
    float* Atot  = Wtot + (size_t)NSC * 1024;
    float* Wsup  = Atot + NSC;
    __hip_bfloat16* Bfrag = (__hip_bfloat16*)(Wsup + (size_t)NSC * 1024);

    prepB_kernel<<<12, 256, 0, stream>>>(Wk, Wv, Wq, Bfrag);
    projA_kernel<<<NCH, 256, 0, stream>>>(X, lr, dec, bk, bv, bq, Bfrag, PROJ, S, P);
    phaseB1_kernel<<<NSC, 256, 0, stream>>>(S, P, Wloc, APb, Wtot, Atot);
    phaseB2_kernel<<<1, 256, 0, stream>>>(Wtot, Atot, Wsup);
    phaseC_kernel<<<NCH, 256, 0, stream>>>(PROJ, lr, dec, Wloc, APb, Wsup, Wo, bo, out);
}

// Round 4
// 167.159 us; speedup vs baseline: 2.2182x; 1.2099x over previous
//
#include <hip/hip_runtime.h>
#include <hip/hip_bf16.h>
#include <math.h>

#define T_STEPS 65536
#define DDIM 256
#define RDIM 32
#define MDIM 52
#define CHUNK 64
#define NCH (T_STEPS / CHUNK)   // 1024 chunks
#define SCH 32                  // chunks per superchunk
#define NSC (NCH / SCH)         // 32 superchunks

typedef short short8 __attribute__((ext_vector_type(8)));   // 8 bf16 (4 VGPRs)
typedef float f32x4  __attribute__((ext_vector_type(4)));   // MFMA acc

union bf8pack { short8 v; __hip_bfloat16 h[8]; };

// ---------------------------------------------------------------------------
// K0: pack W = [Wk;Wv;Wq] (96x256 fp32) into MFMA B-fragment order, bf16.
// Bfrag[((c*8+kb)*64+lane)*8 + j] = bf16( W[16c+(lane&15)][kb*32+(lane>>4)*8+j] )
// ---------------------------------------------------------------------------
__global__ __launch_bounds__(256) void prepB_kernel(
    const float* __restrict__ Wk, const float* __restrict__ Wv,
    const float* __restrict__ Wq, __hip_bfloat16* __restrict__ Bfrag)
{
    const int idx = blockIdx.x * 256 + threadIdx.x;   // 0..3071
    if (idx >= 6 * 8 * 64) return;
    const int lane = idx & 63;
    const int kb   = (idx >> 6) & 7;
    const int c    = idx >> 9;
    const int row  = 16 * c + (lane & 15);            // 0..95
    const int k0   = kb * 32 + (lane >> 4) * 8;       // 0..248
    const float* src = (row < 32) ? (Wk + (size_t)row * DDIM)
                     : (row < 64) ? (Wv + (size_t)(row - 32) * DDIM)
                                  : (Wq + (size_t)(row - 64) * DDIM);
    bf8pack p;
#pragma unroll
    for (int j = 0; j < 8; j++) p.h[j] = __float2bfloat16(src[k0 + j]);
    *(short8*)(Bfrag + (size_t)idx * 8) = p.v;
}

// ---------------------------------------------------------------------------
// K1: MFMA projections (64x96x256 per block) fused with phase A.
// Outputs pre-scaled bf16 planes:
//   Ktil[t][r] = (l_t/b_t) k_t[r],  Qtil[t][r] = b_t q_t[r],  VT[r][t] = v_t[r]
// plus S = P * sum_s ktil_s v_s^T and P per chunk.
// ---------------------------------------------------------------------------
__global__ __launch_bounds__(256) void projA_kernel(
    const float* __restrict__ X,
    const float* __restrict__ lr, const float* __restrict__ decay,
    const float* __restrict__ bk, const float* __restrict__ bv,
    const float* __restrict__ bq,
    const __hip_bfloat16* __restrict__ Bfrag,
    __hip_bfloat16* __restrict__ Ktil, __hip_bfloat16* __restrict__ Qtil,
    __hip_bfloat16* __restrict__ VTg,
    float* __restrict__ Schunk, float* __restrict__ Pchunk)
{
    __shared__ float ks[CHUNK][36];   // k̃ = (l/b) k
    __shared__ float vs[CHUNK][36];   // v
    __shared__ float qs[CHUNK][36];   // q̃ = b q
    __shared__ float bbS[CHUNK], llS[CHUNK];

    const int tid  = threadIdx.x;
    const int wv   = tid >> 6;        // wave id 0..3 -> row-tile
    const int lane = tid & 63;
    const int ch   = blockIdx.x;
    const int t0   = ch * CHUNK;

    // wave 0: decay cumprod via shfl prefix (CHUNK == wavefront == 64)
    if (wv == 0) {
        float b = 1.f - decay[t0 + lane];
        float l = lr[t0 + lane];
#pragma unroll
        for (int d = 1; d < 64; d <<= 1) {
            float o = __shfl_up(b, d, 64);
            if (lane >= d) b *= o;
        }
        bbS[lane] = b; llS[lane] = l;
    }

    // --- MFMA GEMM: C[64x96] = X_tile[64x256] * W^T ---
    const int m  = lane & 15;
    const int q4 = lane >> 4;
    const float* xrow = X + (size_t)(t0 + 16 * wv + m) * DDIM + q4 * 8;

    f32x4 acc[6];
#pragma unroll
    for (int c = 0; c < 6; c++) acc[c] = (f32x4){0.f, 0.f, 0.f, 0.f};

#pragma unroll
    for (int kb = 0; kb < 8; kb++) {
        float4 a0 = *(const float4*)(xrow + kb * 32);
        float4 a1 = *(const float4*)(xrow + kb * 32 + 4);
        bf8pack ap;
        ap.h[0] = __float2bfloat16(a0.x); ap.h[1] = __float2bfloat16(a0.y);
        ap.h[2] = __float2bfloat16(a0.z); ap.h[3] = __float2bfloat16(a0.w);
        ap.h[4] = __float2bfloat16(a1.x); ap.h[5] = __float2bfloat16(a1.y);
        ap.h[6] = __float2bfloat16(a1.z); ap.h[7] = __float2bfloat16(a1.w);
#pragma unroll
        for (int c = 0; c < 6; c++) {
            short8 bf = *(const short8*)(Bfrag + ((size_t)(c * 8 + kb) * 64 + lane) * 8);
            acc[c] = __builtin_amdgcn_mfma_f32_16x16x32_bf16(ap.v, bf, acc[c], 0, 0, 0);
        }
    }

    __syncthreads();                  // bb/ll ready
    const float P = bbS[63];

    // scatter accumulators into LDS with per-row scaling
#pragma unroll
    for (int c = 0; c < 6; c++) {
        const int colg = 16 * c + m;
        const float bias = (colg < 32) ? bk[colg]
                         : (colg < 64) ? bv[colg - 32] : bq[colg - 64];
#pragma unroll
        for (int r = 0; r < 4; r++) {
            const int sloc = 16 * wv + 4 * q4 + r;
            const float val = acc[c][r] + bias;
            if (c < 2)      ks[sloc][colg]      = val * (llS[sloc] / bbS[sloc]);
            else if (c < 4) vs[sloc][colg - 32] = val;
            else            qs[sloc][colg - 64] = val * bbS[sloc];
        }
    }
    __syncthreads();

    // coalesced bf16 plane writes
    {
        const int s = tid >> 2, g = (tid & 3) * 8;
        bf8pack pk, pq;
#pragma unroll
        for (int u = 0; u < 8; u++) {
            pk.h[u] = __float2bfloat16(ks[s][g + u]);
            pq.h[u] = __float2bfloat16(qs[s][g + u]);
        }
        *(short8*)(Ktil + (size_t)(t0 + s) * 32 + g) = pk.v;
        *(short8*)(Qtil + (size_t)(t0 + s) * 32 + g) = pq.v;
    }
    {
        const int r = tid >> 3, g = (tid & 7) * 8;
        bf8pack pv;
#pragma unroll
        for (int u = 0; u < 8; u++) pv.h[u] = __float2bfloat16(vs[g + u][r]);
        *(short8*)(VTg + (size_t)r * T_STEPS + t0 + g) = pv.v;
    }

    // phase A: S[a][b] = P * sum_s k̃[s][a] v[s][b]
    const int b  = tid & 31;
    const int ag = tid >> 5;          // a = ag + 8i
    float a2[4] = {0.f, 0.f, 0.f, 0.f};
    for (int s = 0; s < CHUNK; s++) {
        float vvv = vs[s][b];
#pragma unroll
        for (int i = 0; i < 4; i++) a2[i] += ks[s][ag + 8 * i] * vvv;
    }
    float* Sout = Schunk + (size_t)ch * 1024;
#pragma unroll
    for (int i = 0; i < 4; i++) Sout[(ag + 8 * i) * 32 + b] = P * a2[i];
    if (tid == 0) Pchunk[ch] = P;
}

// ---------------------------------------------------------------------------
// K2 (B1): local scan inside each superchunk (32 seq iters).
// ---------------------------------------------------------------------------
__global__ __launch_bounds__(256) void phaseB1_kernel(
    const float* __restrict__ Schunk, const float* __restrict__ Pchunk,
    float* __restrict__ Wlocal, float* __restrict__ AP,
    float* __restrict__ Wtotal, float* __restrict__ Atot)
{
    const int sc  = blockIdx.x;
    const int tid = threadIdx.x;
    const int e4  = tid * 4;
    float4 w = make_float4(0.f, 0.f, 0.f, 0.f);
    float  a = 1.f;
#pragma unroll 4
    for (int c = 0; c < SCH; c++) {
        const int ch = sc * SCH + c;
        const float p = Pchunk[ch];
        if (tid == 0) AP[ch] = a;
        *(float4*)(Wlocal + (size_t)ch * 1024 + e4) = w;
        float4 s = *(const float4*)(Schunk + (size_t)ch * 1024 + e4);
        w.x = p * w.x + s.x;  w.y = p * w.y + s.y;
        w.z = p * w.z + s.z;  w.w = p * w.w + s.w;
        a *= p;
    }
    *(float4*)(Wtotal + (size_t)sc * 1024 + e4) = w;
    if (tid == 0) Atot[sc] = a;
}

// ---------------------------------------------------------------------------
// K3 (B2): scan over the 32 superchunk totals.
// ---------------------------------------------------------------------------
__global__ __launch_bounds__(256) void phaseB2_kernel(
    const float* __restrict__ Wtotal, const float* __restrict__ Atot,
    float* __restrict__ Wsuper)
{
    const int tid = threadIdx.x;
    const int e4  = tid * 4;
    float4 w = make_float4(0.f, 0.f, 0.f, 0.f);
#pragma unroll 4
    for (int s = 0; s < NSC; s++) {
        *(float4*)(Wsuper + (size_t)s * 1024 + e4) = w;
        const float p = Atot[s];
        float4 t = *(const float4*)(Wtotal + (size_t)s * 1024 + e4);
        w.x = p * w.x + t.x;  w.y = p * w.y + t.y;
        w.z = p * w.z + t.z;  w.w = p * w.w + t.w;
    }
}

// ---------------------------------------------------------------------------
// K4 (phase C): MFMA flash-style intra-chunk attention.
//   scores = Q̃ K̃^T (mask s<=t)  [4 MFMAs/wave, frags direct from global]
//   fast   = [Sc | Q̃] x [[V],[Wst]]  (64x32x96)  [6 MFMAs/wave]
//   out    = 1 + tanh(fast Wo^T + bo)   [VALU, fp32]
// LDS ~29KB, 2 barriers.
// ---------------------------------------------------------------------------
__global__ __launch_bounds__(256) void phaseC_kernel(
    const __hip_bfloat16* __restrict__ Ktil,
    const __hip_bfloat16* __restrict__ Qtil,
    const __hip_bfloat16* __restrict__ VTg,
    const float* __restrict__ Wlocal, const float* __restrict__ AP,
    const float* __restrict__ Wsuper,
    const float* __restrict__ Wo, const float* __restrict__ bo,
    float* __restrict__ out)
{
    __shared__ __hip_bfloat16 scb[CHUNK][72];   // masked scores, bf16
    __shared__ __hip_bfloat16 WstT[32][40];     // Wst^T, bf16
    __shared__ float fastS[CHUNK][36];          // fast_out, fp32
    __shared__ float Wos[MDIM][33];
    __shared__ float bos[MDIM];

    const int tid  = threadIdx.x;
    const int wv   = tid >> 6;
    const int lane = tid & 63;
    const int l15  = lane & 15;
    const int q4   = lane >> 4;
    const int ch   = blockIdx.x;
    const int t0   = ch * CHUNK;

    // stage Wst^T = (AP*Wsuper + Wlocal)^T  (bf16)
    {
        const int scid = ch / SCH;
        const float ap = AP[ch];
        const int a  = tid >> 3;
        const int r0 = (tid & 7) * 4;
        float4 wl = *(const float4*)(Wlocal + (size_t)ch * 1024 + tid * 4);
        float4 wu = *(const float4*)(Wsuper + (size_t)scid * 1024 + tid * 4);
        WstT[r0 + 0][a] = __float2bfloat16(ap * wu.x + wl.x);
        WstT[r0 + 1][a] = __float2bfloat16(ap * wu.y + wl.y);
        WstT[r0 + 2][a] = __float2bfloat16(ap * wu.z + wl.z);
        WstT[r0 + 3][a] = __float2bfloat16(ap * wu.w + wl.w);
    }
    for (int f = tid; f < MDIM * 32; f += 256) Wos[f >> 5][f & 31] = Wo[f];
    if (tid < MDIM) bos[tid] = bo[tid];

    // A-fragment: q̃ rows of this wave's t-tile (reused for q̃·Wst)
    const short8 aq = *(const short8*)(Qtil + (size_t)(t0 + 16 * wv + l15) * 32 + q4 * 8);

    // scores: 4 MFMAs (one per s-tile), K=32
    f32x4 sc4[4];
#pragma unroll
    for (int sn = 0; sn < 4; sn++) {
        short8 bk8 = *(const short8*)(Ktil + (size_t)(t0 + 16 * sn + l15) * 32 + q4 * 8);
        sc4[sn] = __builtin_amdgcn_mfma_f32_16x16x32_bf16(
            aq, bk8, (f32x4){0.f, 0.f, 0.f, 0.f}, 0, 0, 0);
    }
    // mask (s<=t) + bf16 store to LDS
#pragma unroll
    for (int sn = 0; sn < 4; sn++) {
#pragma unroll
        for (int rr = 0; rr < 4; rr++) {
            const int t = 16 * wv + 4 * q4 + rr;
            const int s = 16 * sn + l15;
            scb[t][s] = __float2bfloat16((s <= t) ? sc4[sn][rr] : 0.f);
        }
    }
    __syncthreads();   // scb + WstT ready

    // fast = Sc·V + Q̃·Wst : 64x32, K=96
    f32x4 fa[2] = {(f32x4){0.f,0.f,0.f,0.f}, (f32x4){0.f,0.f,0.f,0.f}};
#pragma unroll
    for (int kb = 0; kb < 2; kb++) {
        short8 ap8 = *(const short8*)(&scb[16 * wv + l15][kb * 32 + q4 * 8]);
#pragma unroll
        for (int rn = 0; rn < 2; rn++) {
            short8 bv8 = *(const short8*)(VTg + (size_t)(16 * rn + l15) * T_STEPS
                                          + t0 + kb * 32 + q4 * 8);
            fa[rn] = __builtin_amdgcn_mfma_f32_16x16x32_bf16(ap8, bv8, fa[rn], 0, 0, 0);
        }
    }
#pragma unroll
    for (int rn = 0; rn < 2; rn++) {
        short8 bw8 = *(const short8*)(&WstT[16 * rn + l15][q4 * 8]);
        fa[rn] = __builtin_amdgcn_mfma_f32_16x16x32_bf16(aq, bw8, fa[rn], 0, 0, 0);
    }
    // fast -> LDS (fp32)
#pragma unroll
    for (int rn = 0; rn < 2; rn++)
#pragma unroll
        for (int rr = 0; rr < 4; rr++)
            fastS[16 * wv + 4 * q4 + rr][16 * rn + l15] = fa[rn][rr];
    __syncthreads();

    // epilogue: out = 1 + tanh(fast @ Wo^T + bo) = 2/(1+exp(-2raw))
    for (int f = tid; f < CHUNK * MDIM; f += 256) {
        const int t = f / MDIM, mm = f % MDIM;
        float acc = bos[mm];
#pragma unroll
        for (int r = 0; r < 32; r += 4) {
            acc += fastS[t][r]     * Wos[mm][r]
                 + fastS[t][r + 1] * Wos[mm][r + 1]
                 + fastS[t][r + 2] * Wos[mm][r + 2]
                 + fastS[t][r + 3] * Wos[mm][r + 3];
        }
        out[(size_t)(t0 + t) * MDIM + mm] = 2.0f / (1.0f + __expf(-2.0f * acc));
    }
}

// ---------------------------------------------------------------------------
extern "C" void kernel_launch(void* const* d_in, const int* in_sizes, int n_in,
                              void* d_out, int out_size, void* d_ws, size_t ws_size,
                              hipStream_t stream) {
    (void)in_sizes; (void)n_in; (void)out_size; (void)ws_size;
    const float* X   = (const float*)d_in[0];
    const float* lr  = (const float*)d_in[1];
    const float* dec = (const float*)d_in[2];
    const float* Wk  = (const float*)d_in[3];
    const float* bk  = (const float*)d_in[4];
    const float* Wv  = (const float*)d_in[5];
    const float* bv  = (const float*)d_in[6];
    const float* Wq  = (const float*)d_in[7];
    const float* bq  = (const float*)d_in[8];
    const float* Wo  = (const float*)d_in[9];
    const float* bo  = (const float*)d_in[10];
    float* out = (float*)d_out;

    // workspace (floats unless noted):
    // S[NCH*1024] | P | AP | Wlocal[NCH*1024] | Wtotal[NSC*1024] | Atot
    // | Wsuper[NSC*1024] | Ktil(bf16 T*32) | Qtil(bf16) | VT(bf16 32*T) | Bfrag(bf16)
    float* ws    = (float*)d_ws;
    float* S     = ws;
    float* P     = S + (size_t)NCH * 1024;
    float* APb   = P + NCH;
    float* Wloc  = APb + NCH;
    float* Wtot  = Wloc + (size_t)NCH * 1024;
    float* Atot  = Wtot + (size_t)NSC * 1024;
    float* Wsup  = Atot + NSC;
    __hip_bfloat16* Ktil  = (__hip_bfloat16*)(Wsup + (size_t)NSC * 1024);
    __hip_bfloat16* Qtil  = Ktil + (size_t)T_STEPS * 32;
    __hip_bfloat16* VTg   = Qtil + (size_t)T_STEPS * 32;
    __hip_bfloat16* Bfrag = VTg + (size_t)T_STEPS * 32;

    prepB_kernel<<<12, 256, 0, stream>>>(Wk, Wv, Wq, Bfrag);
    projA_kernel<<<NCH, 256, 0, stream>>>(X, lr, dec, bk, bv, bq, Bfrag,
                                          Ktil, Qtil, VTg, S, P);
    phaseB1_kernel<<<NSC, 256, 0, stream>>>(S, P, Wloc, APb, Wtot, Atot);
    phaseB2_kernel<<<1, 256, 0, stream>>>(Wtot, Atot, Wsup);
    phaseC_kernel<<<NCH, 256, 0, stream>>>(Ktil, Qtil, VTg, Wloc, APb, Wsup,
                                           Wo, bo, out);
}

// Round 5
// 154.030 us; speedup vs baseline: 2.4073x; 1.0852x over previous
//
#include <hip/hip_runtime.h>
#include <hip/hip_bf16.h>
#include <math.h>

#define T_STEPS 65536
#define DDIM 256
#define RDIM 32
#define MDIM 52
#define CHUNK 64
#define NCH (T_STEPS / CHUNK)   // 1024 chunks
#define SCH 32                  // chunks per superchunk
#define NSC (NCH / SCH)         // 32 superchunks

typedef short short8 __attribute__((ext_vector_type(8)));   // 8 bf16 (4 VGPRs)
typedef float f32x4  __attribute__((ext_vector_type(4)));   // MFMA acc

union bf8pack { short8 v; __hip_bfloat16 h[8]; };

// ---------------------------------------------------------------------------
// K0: pack W = [Wk;Wv;Wq] (96x256) into MFMA B-frag order (bf16), and
// Wo (52x32, zero-padded to 64 rows) into WoFrag.
// Frag convention (validated R3/R4): frag[(tile*nK + kb)*64 + lane][j] =
//   M[16*tile + (lane&15)][kb*32 + (lane>>4)*8 + j]
// ---------------------------------------------------------------------------
__global__ __launch_bounds__(256) void prepB_kernel(
    const float* __restrict__ Wk, const float* __restrict__ Wv,
    const float* __restrict__ Wq, const float* __restrict__ Wo,
    __hip_bfloat16* __restrict__ Bfrag, __hip_bfloat16* __restrict__ WoFrag)
{
    const int idx = blockIdx.x * 256 + threadIdx.x;
    if (idx < 6 * 8 * 64) {
        const int lane = idx & 63;
        const int kb   = (idx >> 6) & 7;
        const int c    = idx >> 9;
        const int row  = 16 * c + (lane & 15);            // 0..95
        const int k0   = kb * 32 + (lane >> 4) * 8;       // 0..248
        const float* src = (row < 32) ? (Wk + (size_t)row * DDIM)
                         : (row < 64) ? (Wv + (size_t)(row - 32) * DDIM)
                                      : (Wq + (size_t)(row - 64) * DDIM);
        bf8pack p;
#pragma unroll
        for (int j = 0; j < 8; j++) p.h[j] = __float2bfloat16(src[k0 + j]);
        *(short8*)(Bfrag + (size_t)idx * 8) = p.v;
    } else if (idx < 6 * 8 * 64 + 4 * 64) {
        const int i2   = idx - 6 * 8 * 64;                // 0..255
        const int lane = i2 & 63;
        const int c    = i2 >> 6;                         // n-tile 0..3
        const int mm   = 16 * c + (lane & 15);            // 0..63 (pad >=52)
        const int k0   = (lane >> 4) * 8;                 // 0..24
        bf8pack p;
#pragma unroll
        for (int j = 0; j < 8; j++)
            p.h[j] = __float2bfloat16(mm < MDIM ? Wo[(size_t)mm * 32 + k0 + j] : 0.f);
        *(short8*)(WoFrag + (size_t)i2 * 8) = p.v;
    }
}

// ---------------------------------------------------------------------------
// K1: MFMA projections (64x96x256 per block) fused with phase A.
// Outputs bf16 planes Ktil[t][32] ((l/b)k), Qtil[t][32] (b q), VT[32][T] (v),
// and S = P * k̃^T v  via MFMA, P per chunk.
// ---------------------------------------------------------------------------
__global__ __launch_bounds__(256) void projA_kernel(
    const float* __restrict__ X,
    const float* __restrict__ lr, const float* __restrict__ decay,
    const float* __restrict__ bk, const float* __restrict__ bv,
    const float* __restrict__ bq,
    const __hip_bfloat16* __restrict__ Bfrag,
    __hip_bfloat16* __restrict__ Ktil, __hip_bfloat16* __restrict__ Qtil,
    __hip_bfloat16* __restrict__ VTg,
    float* __restrict__ Schunk, float* __restrict__ Pchunk)
{
    __shared__ __hip_bfloat16 kR[CHUNK][40];  // k̃ row-major  (plane copy)
    __shared__ __hip_bfloat16 qR[CHUNK][40];  // q̃ row-major  (plane copy)
    __shared__ __hip_bfloat16 kT[32][72];     // k̃^T [a][s]   (S-MFMA A-frag)
    __shared__ __hip_bfloat16 vT[32][72];     // v^T  [r][s]   (S-MFMA B-frag + VT plane)
    __shared__ float bbS[CHUNK], llS[CHUNK], biasS[96];

    const int tid  = threadIdx.x;
    const int wv   = tid >> 6;        // wave id 0..3 -> row-tile
    const int lane = tid & 63;
    const int l15  = lane & 15;
    const int q4   = lane >> 4;
    const int ch   = blockIdx.x;
    const int t0   = ch * CHUNK;

    // wave 0: decay cumprod via shfl prefix (CHUNK == wavefront == 64)
    if (wv == 0) {
        float b = 1.f - decay[t0 + lane];
        float l = lr[t0 + lane];
#pragma unroll
        for (int d = 1; d < 64; d <<= 1) {
            float o = __shfl_up(b, d, 64);
            if (lane >= d) b *= o;
        }
        bbS[lane] = b; llS[lane] = l;
    }
    if (tid < 96) {
        biasS[tid] = (tid < 32) ? bk[tid] : (tid < 64) ? bv[tid - 32] : bq[tid - 64];
    }

    // --- MFMA GEMM: C[64x96] = X_tile[64x256] * W^T ---
    const float* xrow = X + (size_t)(t0 + 16 * wv + l15) * DDIM + q4 * 8;

    f32x4 acc[6];
#pragma unroll
    for (int c = 0; c < 6; c++) acc[c] = (f32x4){0.f, 0.f, 0.f, 0.f};

#pragma unroll
    for (int kb = 0; kb < 8; kb++) {
        float4 a0 = *(const float4*)(xrow + kb * 32);
        float4 a1 = *(const float4*)(xrow + kb * 32 + 4);
        bf8pack ap;
        ap.h[0] = __float2bfloat16(a0.x); ap.h[1] = __float2bfloat16(a0.y);
        ap.h[2] = __float2bfloat16(a0.z); ap.h[3] = __float2bfloat16(a0.w);
        ap.h[4] = __float2bfloat16(a1.x); ap.h[5] = __float2bfloat16(a1.y);
        ap.h[6] = __float2bfloat16(a1.z); ap.h[7] = __float2bfloat16(a1.w);
#pragma unroll
        for (int c = 0; c < 6; c++) {
            short8 bf = *(const short8*)(Bfrag + ((size_t)(c * 8 + kb) * 64 + lane) * 8);
            acc[c] = __builtin_amdgcn_mfma_f32_16x16x32_bf16(ap.v, bf, acc[c], 0, 0, 0);
        }
    }

    __syncthreads();                  // bb/ll/bias ready
    const float P = bbS[63];

    // scatter accumulators into bf16 LDS tiles with per-row scaling
#pragma unroll
    for (int c = 0; c < 6; c++) {
        const int colg = 16 * c + l15;
        const float bias = biasS[colg];
#pragma unroll
        for (int r = 0; r < 4; r++) {
            const int sloc = 16 * wv + 4 * q4 + r;
            const float val = acc[c][r] + bias;
            if (c < 2) {
                __hip_bfloat16 h = __float2bfloat16(val * (llS[sloc] / bbS[sloc]));
                kR[sloc][colg] = h;
                kT[colg][sloc] = h;
            } else if (c < 4) {
                vT[colg - 32][sloc] = __float2bfloat16(val);
            } else {
                qR[sloc][colg - 64] = __float2bfloat16(val * bbS[sloc]);
            }
        }
    }
    __syncthreads();

    // coalesced bf16 plane writes
    {
        const int s = tid >> 2, g = (tid & 3) * 8;
        *(short8*)(Ktil + (size_t)(t0 + s) * 32 + g) = *(const short8*)(&kR[s][g]);
        *(short8*)(Qtil + (size_t)(t0 + s) * 32 + g) = *(const short8*)(&qR[s][g]);
    }
    {
        const int r = tid >> 3, g = (tid & 7) * 8;
        *(short8*)(VTg + (size_t)r * T_STEPS + t0 + g) = *(const short8*)(&vT[r][g]);
    }

    // phase A via MFMA: S[a][b] = P * sum_s kT[a][s] vT[b][s]
    // wave wv -> quadrant (am = wv&1, bn = wv>>1)
    {
        const int am = wv & 1, bn = wv >> 1;
        f32x4 sacc = (f32x4){0.f, 0.f, 0.f, 0.f};
#pragma unroll
        for (int k2 = 0; k2 < 2; k2++) {
            short8 aF = *(const short8*)(&kT[16 * am + l15][k2 * 32 + q4 * 8]);
            short8 bF = *(const short8*)(&vT[16 * bn + l15][k2 * 32 + q4 * 8]);
            sacc = __builtin_amdgcn_mfma_f32_16x16x32_bf16(aF, bF, sacc, 0, 0, 0);
        }
        float* Sout = Schunk + (size_t)ch * 1024;
#pragma unroll
        for (int rr = 0; rr < 4; rr++) {
            const int a = 16 * am + 4 * q4 + rr;
            const int b = 16 * bn + l15;
            Sout[a * 32 + b] = P * sacc[rr];
        }
    }
    if (tid == 0) Pchunk[ch] = P;
}

// ---------------------------------------------------------------------------
// K2 (B1): local scan inside each superchunk (32 seq iters).
// ---------------------------------------------------------------------------
__global__ __launch_bounds__(256) void phaseB1_kernel(
    const float* __restrict__ Schunk, const float* __restrict__ Pchunk,
    float* __restrict__ Wlocal, float* __restrict__ AP,
    float* __restrict__ Wtotal, float* __restrict__ Atot)
{
    const int sc  = blockIdx.x;
    const int tid = threadIdx.x;
    const int e4  = tid * 4;
    float4 w = make_float4(0.f, 0.f, 0.f, 0.f);
    float  a = 1.f;
#pragma unroll 4
    for (int c = 0; c < SCH; c++) {
        const int ch = sc * SCH + c;
        const float p = Pchunk[ch];
        if (tid == 0) AP[ch] = a;
        *(float4*)(Wlocal + (size_t)ch * 1024 + e4) = w;
        float4 s = *(const float4*)(Schunk + (size_t)ch * 1024 + e4);
        w.x = p * w.x + s.x;  w.y = p * w.y + s.y;
        w.z = p * w.z + s.z;  w.w = p * w.w + s.w;
        a *= p;
    }
    *(float4*)(Wtotal + (size_t)sc * 1024 + e4) = w;
    if (tid == 0) Atot[sc] = a;
}

// ---------------------------------------------------------------------------
// K3 (B2): scan over the 32 superchunk totals.
// ---------------------------------------------------------------------------
__global__ __launch_bounds__(256) void phaseB2_kernel(
    const float* __restrict__ Wtotal, const float* __restrict__ Atot,
    float* __restrict__ Wsuper)
{
    const int tid = threadIdx.x;
    const int e4  = tid * 4;
    float4 w = make_float4(0.f, 0.f, 0.f, 0.f);
#pragma unroll 4
    for (int s = 0; s < NSC; s++) {
        *(float4*)(Wsuper + (size_t)s * 1024 + e4) = w;
        const float p = Atot[s];
        float4 t = *(const float4*)(Wtotal + (size_t)s * 1024 + e4);
        w.x = p * w.x + t.x;  w.y = p * w.y + t.y;
        w.z = p * w.z + t.z;  w.w = p * w.w + t.w;
    }
}

// ---------------------------------------------------------------------------
// K4 (phase C): all-MFMA intra-chunk attention + epilogue.
//   scores = Q̃ K̃^T (mask s<=t)            [4 MFMAs/wave, frags from global]
//   fast   = Sc·V + Q̃·Wst (64x32, K=96)    [6 MFMAs/wave]
//   out    = 1 + tanh(fast Wo^T + bo)       [4 MFMAs/wave + exp]
// ---------------------------------------------------------------------------
__global__ __launch_bounds__(256) void phaseC_kernel(
    const __hip_bfloat16* __restrict__ Ktil,
    const __hip_bfloat16* __restrict__ Qtil,
    const __hip_bfloat16* __restrict__ VTg,
    const float* __restrict__ Wlocal, const float* __restrict__ AP,
    const float* __restrict__ Wsuper,
    const __hip_bfloat16* __restrict__ WoFrag, const float* __restrict__ bo,
    float* __restrict__ out)
{
    __shared__ __hip_bfloat16 scb[CHUNK][72];   // masked scores, bf16
    __shared__ __hip_bfloat16 WstT[32][40];     // Wst^T, bf16
    __shared__ __hip_bfloat16 fastB[CHUNK][40]; // fast_out, bf16 (A-frag for epi)
    __shared__ float bosS[MDIM];

    const int tid  = threadIdx.x;
    const int wv   = tid >> 6;
    const int lane = tid & 63;
    const int l15  = lane & 15;
    const int q4   = lane >> 4;
    const int ch   = blockIdx.x;
    const int t0   = ch * CHUNK;

    // stage Wst^T = (AP*Wsuper + Wlocal)^T  (bf16)
    {
        const int scid = ch / SCH;
        const float ap = AP[ch];
        const int a  = tid >> 3;
        const int r0 = (tid & 7) * 4;
        float4 wl = *(const float4*)(Wlocal + (size_t)ch * 1024 + tid * 4);
        float4 wu = *(const float4*)(Wsuper + (size_t)scid * 1024 + tid * 4);
        WstT[r0 + 0][a] = __float2bfloat16(ap * wu.x + wl.x);
        WstT[r0 + 1][a] = __float2bfloat16(ap * wu.y + wl.y);
        WstT[r0 + 2][a] = __float2bfloat16(ap * wu.z + wl.z);
        WstT[r0 + 3][a] = __float2bfloat16(ap * wu.w + wl.w);
    }
    if (tid < MDIM) bosS[tid] = bo[tid];

    // A-fragment: q̃ rows of this wave's t-tile (reused for q̃·Wst)
    const short8 aq = *(const short8*)(Qtil + (size_t)(t0 + 16 * wv + l15) * 32 + q4 * 8);

    // scores: 4 MFMAs (one per s-tile), K=32
    f32x4 sc4[4];
#pragma unroll
    for (int sn = 0; sn < 4; sn++) {
        short8 bk8 = *(const short8*)(Ktil + (size_t)(t0 + 16 * sn + l15) * 32 + q4 * 8);
        sc4[sn] = __builtin_amdgcn_mfma_f32_16x16x32_bf16(
            aq, bk8, (f32x4){0.f, 0.f, 0.f, 0.f}, 0, 0, 0);
    }
    // mask (s<=t) + bf16 store to LDS
#pragma unroll
    for (int sn = 0; sn < 4; sn++) {
#pragma unroll
        for (int rr = 0; rr < 4; rr++) {
            const int t = 16 * wv + 4 * q4 + rr;
            const int s = 16 * sn + l15;
            scb[t][s] = __float2bfloat16((s <= t) ? sc4[sn][rr] : 0.f);
        }
    }
    __syncthreads();   // scb + WstT ready

    // fast = Sc·V + Q̃·Wst : 64x32, K=96
    f32x4 fa[2] = {(f32x4){0.f,0.f,0.f,0.f}, (f32x4){0.f,0.f,0.f,0.f}};
#pragma unroll
    for (int kb = 0; kb < 2; kb++) {
        short8 ap8 = *(const short8*)(&scb[16 * wv + l15][kb * 32 + q4 * 8]);
#pragma unroll
        for (int rn = 0; rn < 2; rn++) {
            short8 bv8 = *(const short8*)(VTg + (size_t)(16 * rn + l15) * T_STEPS
                                          + t0 + kb * 32 + q4 * 8);
            fa[rn] = __builtin_amdgcn_mfma_f32_16x16x32_bf16(ap8, bv8, fa[rn], 0, 0, 0);
        }
    }
#pragma unroll
    for (int rn = 0; rn < 2; rn++) {
        short8 bw8 = *(const short8*)(&WstT[16 * rn + l15][q4 * 8]);
        fa[rn] = __builtin_amdgcn_mfma_f32_16x16x32_bf16(aq, bw8, fa[rn], 0, 0, 0);
    }
    // fast -> LDS (bf16, A-frag layout source)
#pragma unroll
    for (int rn = 0; rn < 2; rn++)
#pragma unroll
        for (int rr = 0; rr < 4; rr++)
            fastB[16 * wv + 4 * q4 + rr][16 * rn + l15] = __float2bfloat16(fa[rn][rr]);
    __syncthreads();

    // epilogue: out = 1 + tanh(fast @ Wo^T + bo), via 4 MFMAs/wave (K=32)
    {
        const short8 aF = *(const short8*)(&fastB[16 * wv + l15][q4 * 8]);
#pragma unroll
        for (int c = 0; c < 4; c++) {
            short8 bF = *(const short8*)(WoFrag + ((size_t)(c * 64) + lane) * 8);
            f32x4 oc = __builtin_amdgcn_mfma_f32_16x16x32_bf16(
                aF, bF, (f32x4){0.f, 0.f, 0.f, 0.f}, 0, 0, 0);
            const int mm = 16 * c + l15;
            if (mm < MDIM) {
                const float bb = bosS[mm];
#pragma unroll
                for (int rr = 0; rr < 4; rr++) {
                    const int t = 16 * wv + 4 * q4 + rr;
                    out[(size_t)(t0 + t) * MDIM + mm] =
                        2.0f / (1.0f + __expf(-2.0f * (oc[rr] + bb)));
                }
            }
        }
    }
}

// ---------------------------------------------------------------------------
extern "C" void kernel_launch(void* const* d_in, const int* in_sizes, int n_in,
                              void* d_out, int out_size, void* d_ws, size_t ws_size,
                              hipStream_t stream) {
    (void)in_sizes; (void)n_in; (void)out_size; (void)ws_size;
    const float* X   = (const float*)d_in[0];
    const float* lr  = (const float*)d_in[1];
    const float* dec = (const float*)d_in[2];
    const float* Wk  = (const float*)d_in[3];
    const float* bk  = (const float*)d_in[4];
    const float* Wv  = (const float*)d_in[5];
    const float* bv  = (const float*)d_in[6];
    const float* Wq  = (const float*)d_in[7];
    const float* bq  = (const float*)d_in[8];
    const float* Wo  = (const float*)d_in[9];
    const float* bo  = (const float*)d_in[10];
    float* out = (float*)d_out;

    // workspace (floats unless noted):
    // S[NCH*1024] | P | AP | Wlocal[NCH*1024] | Wtotal[NSC*1024] | Atot
    // | Wsuper[NSC*1024] | Ktil(bf16 T*32) | Qtil | VT(bf16 32*T) | Bfrag | WoFrag
    float* ws    = (float*)d_ws;
    float* S     = ws;
    float* P     = S + (size_t)NCH * 1024;
    float* APb   = P + NCH;
    float* Wloc  = APb + NCH;
    float* Wtot  = Wloc + (size_t)NCH * 1024;
    float* Atot  = Wtot + (size_t)NSC * 1024;
    float* Wsup  = Atot + NSC;
    __hip_bfloat16* Ktil   = (__hip_bfloat16*)(Wsup + (size_t)NSC * 1024);
    __hip_bfloat16* Qtil   = Ktil + (size_t)T_STEPS * 32;
    __hip_bfloat16* VTg    = Qtil + (size_t)T_STEPS * 32;
    __hip_bfloat16* Bfrag  = VTg + (size_t)T_STEPS * 32;
    __hip_bfloat16* WoFrag = Bfrag + (size_t)96 * 256;

    prepB_kernel<<<13, 256, 0, stream>>>(Wk, Wv, Wq, Wo, Bfrag, WoFrag);
    projA_kernel<<<NCH, 256, 0, stream>>>(X, lr, dec, bk, bv, bq, Bfrag,
                                          Ktil, Qtil, VTg, S, P);
    phaseB1_kernel<<<NSC, 256, 0, stream>>>(S, P, Wloc, APb, Wtot, Atot);
    phaseB2_kernel<<<1, 256, 0, stream>>>(Wtot, Atot, Wsup);
    phaseC_kernel<<<NCH, 256, 0, stream>>>(Ktil, Qtil, VTg, Wloc, APb, Wsup,
                                           WoFrag, bo, out);
}